// Round 8
// baseline (664.631 us; speedup 1.0000x reference)
//
#include <hip/hip_runtime.h>

// Problem constants
#define S_  2048
#define D_  1024
#define H_  16
#define B_  4

typedef __attribute__((ext_vector_type(8))) short short8;
typedef __attribute__((ext_vector_type(4))) float f32x4;
typedef __attribute__((ext_vector_type(4))) _Float16 half4;
typedef __attribute__((ext_vector_type(8))) _Float16 half8;

__device__ __forceinline__ unsigned short f2bf(float f) {
  unsigned int u = __float_as_uint(f);
  u += 0x7fffu + ((u >> 16) & 1u);      // round-to-nearest-even
  return (unsigned short)(u >> 16);
}
__device__ __forceinline__ unsigned int pack2(float a, float b) {
  return (unsigned int)f2bf(a) | ((unsigned int)f2bf(b) << 16);
}

// 0.125 (1/sqrt(DK)) * log2(e): use exp2 (native v_exp_f32)
#define SCL   0.18033688011112042f
#define EBIAS 12.0f   // keeps e' in fp16 range; cancels in normalization (R2-validated)
#define FIXP  1048576.0f   // 2^20 fixed-point for deterministic column sums

// ---------------------------------------------------------------------------
// x (B,S,D) f32 -> xh (B,H,S,64) bf16 head-major (256 KB contiguous per bh).
// ---------------------------------------------------------------------------
__global__ __launch_bounds__(256) void xcvt(const float* __restrict__ x,
                                            unsigned short* __restrict__ xh) {
  const int n = blockIdx.x;
  const int bh = n >> 5, chunk = n & 31;
  const int b = bh >> 4, h = bh & 15;
  const int r = threadIdx.x >> 2, cg = threadIdx.x & 3;
  const int srow = chunk * 64 + r;
  const float* src = x + ((size_t)b * S_ + srow) * D_ + h * 64 + cg * 16;
  float4 v0 = ((const float4*)src)[0];
  float4 v1 = ((const float4*)src)[1];
  float4 v2 = ((const float4*)src)[2];
  float4 v3 = ((const float4*)src)[3];
  uint4 w0, w1;
  w0.x = pack2(v0.x, v0.y); w0.y = pack2(v0.z, v0.w);
  w0.z = pack2(v1.x, v1.y); w0.w = pack2(v1.z, v1.w);
  w1.x = pack2(v2.x, v2.y); w1.y = pack2(v2.z, v2.w);
  w1.z = pack2(v3.x, v3.y); w1.w = pack2(v3.z, v3.w);
  unsigned short* dst = xh + ((size_t)bh * S_ + srow) * 64 + cg * 16;
  *(uint4*)dst = w0;
  *(uint4*)(dst + 8) = w1;
}

// ---------------------------------------------------------------------------
// Single-pass fused attention, e' staged in LDS as fp16.
// Block = 256 thr (4 waves), ONE 16-row q-tile, full S keys. Wave w computes
// score tiles kt == w (mod 4). K staged in 32-key double-buffered chunks
// (R6's proven stage->sync->compute pattern). exp2(s*SCL-EBIAS) -> ebuf fp16.
// After row-sum reduce: write phase streams 256B-contiguous nt stores of
// normalized attn; colsum pass re-reads ebuf (conflict-free b128) and flushes
// fixed-point u32 atomics (integer-commutative => deterministic).
// LDS 72.3 KB -> 2 blocks/CU: one block writes while the other computes.
// grid = 64 bh * 128 qt = 8192, XCD-swizzled (8 bh per XCD, L2-resident K).
// ---------------------------------------------------------------------------
__global__ __launch_bounds__(256, 2) void attn_fused(
    const unsigned short* __restrict__ xh, const int* __restrict__ sl32,
    float* __restrict__ attn, unsigned int* __restrict__ c32)
{
  __shared__ __align__(16) unsigned short kbuf[2][32 * 64]; // 2 x 4 KB keys
  __shared__ __align__(16) _Float16 ebuf[16][2048];         // 64 KB e' tile
  __shared__ float wbuf[4][16];
  __shared__ float invbuf[16];

  const int n    = blockIdx.x;
  const int xcd  = n & 7;
  const int slot = n >> 3;                 // 0..1023 per XCD
  const int bh   = (slot >> 7) * 8 + xcd;  // 8 bh-slices per XCD
  const int qt   = slot & 127;             // 128 q-tiles of 16 rows
  const int b    = bh >> 4;
  const int tid  = threadIdx.x;
  const int wv   = tid >> 6;
  const int lane = tid & 63;
  const int lo   = lane & 15;
  const int g    = lane >> 4;

  // seq_lens dtype auto-detect (values >= 1024 -> int64 layout has word1==0)
  const bool is64 = (sl32[1] == 0);
  const int seqlen = is64 ? sl32[2 * b] : sl32[b];

  const unsigned short* xk = xh + (size_t)bh * S_ * 64;

  // Q fragment (A-frag): row = lo, k = g*8 + i (+32)
  short8 aq0 = *(const short8*)(xk + (size_t)(qt * 16 + lo) * 64 + g * 8);
  short8 aq1 = *(const short8*)(xk + (size_t)(qt * 16 + lo) * 64 + g * 8 + 32);

  // Staging (32-key chunk = 4 KB): thread t -> local row t>>3, 16B unit t&7,
  // stored XOR-swizzled: unit u -> u ^ (row&7).
  const int slr = tid >> 3, su = tid & 7;
  auto stage = [&](int c) {
    uint4 v = *(const uint4*)(xk + (size_t)(c * 32 + slr) * 64 + su * 8);
    *(uint4*)&kbuf[(c & 1)][slr * 64 + (su ^ (slr & 7)) * 8] = v;
  };

  // ---------------- Single compute pass: QK^T + exp -> ebuf ----------------
  // Wave wv active on chunk c iff (c&1) == (wv>>1); its tile is T = 2c+(wv&1).
  const int myp16 = (wv & 1) * 16;         // local key offset of my tile
  const int mysel = wv >> 1;               // chunk parity I work on
  float rsum[4] = {0.f, 0.f, 0.f, 0.f};
  stage(0);
  __syncthreads();
  for (int c = 0; c < 64; ++c) {
    if (c < 63) stage(c + 1);
    if ((c & 1) == mysel) {
      const int lk = myp16 + lo;           // local key row 0..31
      const int cs = g ^ (lk & 7);
      const unsigned short* kb = &kbuf[c & 1][0];
      short8 b0 = *(const short8*)&kb[lk * 64 + cs * 8];
      short8 b1 = *(const short8*)&kb[lk * 64 + (cs ^ 4) * 8];
      f32x4 acc = {0.f, 0.f, 0.f, 0.f};
      acc = __builtin_amdgcn_mfma_f32_16x16x32_bf16(aq0, b0, acc, 0, 0, 0);
      acc = __builtin_amdgcn_mfma_f32_16x16x32_bf16(aq1, b1, acc, 0, 0, 0);
      const int kg = c * 32 + lk;          // global key/col index
      const bool valid = kg < seqlen;
      float e0 = valid ? exp2f(acc[0] * SCL - EBIAS) : 0.f;
      float e1 = valid ? exp2f(acc[1] * SCL - EBIAS) : 0.f;
      float e2 = valid ? exp2f(acc[2] * SCL - EBIAS) : 0.f;
      float e3 = valid ? exp2f(acc[3] * SCL - EBIAS) : 0.f;
      rsum[0] += e0; rsum[1] += e1; rsum[2] += e2; rsum[3] += e3;
      ebuf[g * 4 + 0][kg] = (_Float16)e0;
      ebuf[g * 4 + 1][kg] = (_Float16)e1;
      ebuf[g * 4 + 2][kg] = (_Float16)e2;
      ebuf[g * 4 + 3][kg] = (_Float16)e3;
    }
    __syncthreads();
  }

  // ---------------- Row sums -> 1/l (cross-lane + cross-wave) ----------------
#pragma unroll
  for (int r = 0; r < 4; ++r) {
    float v = rsum[r];
    v += __shfl_xor(v, 1);
    v += __shfl_xor(v, 2);
    v += __shfl_xor(v, 4);
    v += __shfl_xor(v, 8);
    if (lo == 0) wbuf[wv][g * 4 + r] = v;
  }
  __syncthreads();
  if (tid < 16)
    invbuf[tid] = 1.0f / (wbuf[0][tid] + wbuf[1][tid] + wbuf[2][tid] + wbuf[3][tid]);
  __syncthreads();

  // ---------------- Write phase: fat contiguous nt stores ----------------
  const int wr = tid >> 4;                 // row 0..15
  const int wc = tid & 15;
  const float vr = invbuf[wr];
  float* prow = attn + (size_t)bh * S_ * S_ + (size_t)(qt * 16 + wr) * S_;
#pragma unroll 8
  for (int i = 0; i < 32; ++i) {
    const int col = wc * 4 + i * 64;       // 16 lanes -> 256B contiguous
    half4 h = *(const half4*)&ebuf[wr][col];
    f32x4 v = {(float)h[0] * vr, (float)h[1] * vr,
               (float)h[2] * vr, (float)h[3] * vr};
    __builtin_nontemporal_store(v, (f32x4*)(prow + col));
  }

  // ---------------- Column sums: ebuf re-read + fixed-point atomics -------
  unsigned int* cb = c32 + (size_t)bh * 2048;
  const int c0 = tid * 8;
  float cs0 = 0.f, cs1 = 0.f, cs2 = 0.f, cs3 = 0.f;
  float cs4 = 0.f, cs5 = 0.f, cs6 = 0.f, cs7 = 0.f;
#pragma unroll
  for (int r = 0; r < 16; ++r) {
    const float vr2 = invbuf[r];
    half8 h = *(const half8*)&ebuf[r][c0];
    cs0 += (float)h[0] * vr2; cs1 += (float)h[1] * vr2;
    cs2 += (float)h[2] * vr2; cs3 += (float)h[3] * vr2;
    cs4 += (float)h[4] * vr2; cs5 += (float)h[5] * vr2;
    cs6 += (float)h[6] * vr2; cs7 += (float)h[7] * vr2;
  }
  atomicAdd(&cb[c0 + 0], __float2uint_rn(cs0 * FIXP));
  atomicAdd(&cb[c0 + 1], __float2uint_rn(cs1 * FIXP));
  atomicAdd(&cb[c0 + 2], __float2uint_rn(cs2 * FIXP));
  atomicAdd(&cb[c0 + 3], __float2uint_rn(cs3 * FIXP));
  atomicAdd(&cb[c0 + 4], __float2uint_rn(cs4 * FIXP));
  atomicAdd(&cb[c0 + 5], __float2uint_rn(cs5 * FIXP));
  atomicAdd(&cb[c0 + 6], __float2uint_rn(cs6 * FIXP));
  atomicAdd(&cb[c0 + 7], __float2uint_rn(cs7 * FIXP));
}

// csump[oct][bh][d] = sum over oct's 256 keys of c[bh][k] * xh[bh][k][d]
__global__ __launch_bounds__(256) void csum_k(const unsigned int* __restrict__ c32,
                                              const unsigned short* __restrict__ xh,
                                              float* __restrict__ csump) {
  __shared__ float part[4][64];
  const int bh = blockIdx.x >> 3, oct = blockIdx.x & 7;
  const int seg = threadIdx.x >> 6, d = threadIdx.x & 63;
  const unsigned int* cb = c32 + (size_t)bh * 2048;
  const unsigned short* xb = xh + (size_t)bh * S_ * 64 + d;
  const int k0 = oct * 256 + seg * 64;
  float acc = 0.f;
#pragma unroll 4
  for (int k = k0; k < k0 + 64; ++k) {
    float cv = (float)cb[k] * (1.0f / FIXP);
    float xv = __uint_as_float((unsigned int)xb[(size_t)k * 64] << 16);
    acc += cv * xv;
  }
  part[seg][d] = acc;
  __syncthreads();
  if (threadIdx.x < 64)
    csump[((size_t)oct * 64 + bh) * 64 + d] =
        part[0][d] + part[1][d] + part[2][d] + part[3][d];
}

// out0[b][d] = sum_e csum[b][e] * W[d][e] + S * bias[d], csum = sum of octants
__global__ __launch_bounds__(256) void proj_k(const float* __restrict__ csump,
                                              const float* __restrict__ W,
                                              const float* __restrict__ bias,
                                              float* __restrict__ out0) {
  const int idx = blockIdx.x * 4 + (threadIdx.x >> 6); // (b,d) pair per wave
  const int b = idx >> 10, d = idx & 1023;
  const int lane = threadIdx.x & 63;
  const float* wr = W + (size_t)d * D_;
  float acc = 0.f;
#pragma unroll
  for (int e = 0; e < 16; ++e) {
    const int ei = lane + e * 64;            // e index within D
    const int bhh = b * 16 + (ei >> 6);      // bh of this e
    const int dd = ei & 63;
    float cv = 0.f;
#pragma unroll
    for (int oct = 0; oct < 8; ++oct)
      cv += csump[((size_t)oct * 64 + bhh) * 64 + dd];
    acc += cv * wr[ei];
  }
  acc += __shfl_xor(acc, 32);
  acc += __shfl_xor(acc, 16);
  acc += __shfl_xor(acc, 8);
  acc += __shfl_xor(acc, 4);
  acc += __shfl_xor(acc, 2);
  acc += __shfl_xor(acc, 1);
  if (lane == 0) out0[idx] = acc + 2048.0f * bias[d];
}

extern "C" void kernel_launch(void* const* d_in, const int* in_sizes, int n_in,
                              void* d_out, int out_size, void* d_ws, size_t ws_size,
                              hipStream_t stream) {
  const float* x    = (const float*)d_in[0];
  const int*   sl   = (const int*)d_in[1];
  const float* W    = (const float*)d_in[2];
  const float* bias = (const float*)d_in[3];

  float* out0 = (float*)d_out;
  float* attn = out0 + B_ * D_;

  unsigned int* c32 = (unsigned int*)d_ws;               // 64*2048 u32 = 512 KB
  float* csump = (float*)(c32 + 64 * 2048);              // 8*64*64 f32 = 128 KB
  unsigned short* xh = (unsigned short*)(csump + 8 * 64 * 64); // bf16, 16 MB

  (void)hipMemsetAsync(c32, 0, (size_t)64 * 2048 * 4, stream);
  hipLaunchKernelGGL(xcvt,       dim3(2048), dim3(256), 0, stream, x, xh);
  hipLaunchKernelGGL(attn_fused, dim3(8192), dim3(256), 0, stream, xh, sl, attn, c32);
  hipLaunchKernelGGL(csum_k,     dim3(512),  dim3(256), 0, stream, c32, xh, csump);
  hipLaunchKernelGGL(proj_k,     dim3(1024), dim3(256), 0, stream, csump, W, bias, out0);
}

// Round 9
// 322.232 us; speedup vs baseline: 2.0626x; 2.0626x over previous
//
#include <hip/hip_runtime.h>

// Problem constants
#define S_  2048
#define D_  1024
#define H_  16
#define B_  4

typedef __attribute__((ext_vector_type(8))) short short8;
typedef __attribute__((ext_vector_type(4))) float f32x4;

__device__ __forceinline__ unsigned short f2bf(float f) {
  unsigned int u = __float_as_uint(f);
  u += 0x7fffu + ((u >> 16) & 1u);      // round-to-nearest-even
  return (unsigned short)(u >> 16);
}
__device__ __forceinline__ unsigned int pack2(float a, float b) {
  return (unsigned int)f2bf(a) | ((unsigned int)f2bf(b) << 16);
}
__device__ __forceinline__ float h2f(unsigned int u, int shft) {
  unsigned short hs = (unsigned short)(u >> shft);
  return (float)__builtin_bit_cast(_Float16, hs);
}

// 0.125 (1/sqrt(DK)) * log2(e): use exp2 (native v_exp_f32)
#define SCL   0.18033688011112042f
#define EBIAS 12.0f   // keeps e' in fp16 range; cancels in softmax (R2/R8-validated)

// ---------------------------------------------------------------------------
// x (B,S,D) f32 -> xh (B,H,S,64) bf16 head-major (256 KB contiguous per bh).
// ---------------------------------------------------------------------------
__global__ __launch_bounds__(256) void xcvt(const float* __restrict__ x,
                                            unsigned short* __restrict__ xh) {
  const int n = blockIdx.x;
  const int bh = n >> 5, chunk = n & 31;
  const int b = bh >> 4, h = bh & 15;
  const int r = threadIdx.x >> 2, cg = threadIdx.x & 3;
  const int srow = chunk * 64 + r;
  const float* src = x + ((size_t)b * S_ + srow) * D_ + h * 64 + cg * 16;
  float4 v0 = ((const float4*)src)[0];
  float4 v1 = ((const float4*)src)[1];
  float4 v2 = ((const float4*)src)[2];
  float4 v3 = ((const float4*)src)[3];
  uint4 w0, w1;
  w0.x = pack2(v0.x, v0.y); w0.y = pack2(v0.z, v0.w);
  w0.z = pack2(v1.x, v1.y); w0.w = pack2(v1.z, v1.w);
  w1.x = pack2(v2.x, v2.y); w1.y = pack2(v2.z, v2.w);
  w1.z = pack2(v3.x, v3.y); w1.w = pack2(v3.z, v3.w);
  unsigned short* dst = xh + ((size_t)bh * S_ + srow) * 64 + cg * 16;
  *(uint4*)dst = w0;
  *(uint4*)(dst + 8) = w1;
}

// ---------------------------------------------------------------------------
// Single-pass fused attention, e' in LDS as packed fp16 row-pairs.
// Block = 256 thr (4 waves), one 16-row q-tile, full S keys.
// Compute: 32 rounds of 64-key chunks; wave w owns tile w (ALL waves busy);
// reg-prefetch(c+1) before compute(c), commit after sync (latency hidden).
// e' = exp2(s*SCL-EBIAS) packed (row2r2,row2r2+1) u32 -> ebuf[8][2048],
// col XOR-swizzled by ((r2&6)<<2) -> 2-way banks max (free).
// Write phase: per-row b128 ebuf reads -> 256B-contiguous nt stores.
// Column sums: in-thread over all 16 rows -> fp16 cpart (no atomics,
// deterministic). LDS 72.6 KB -> 2 blocks/CU (stores overlap next compute).
// grid = 64 bh * 128 qt = 8192, XCD-swizzled (8 bh per XCD, L2-resident K).
// ---------------------------------------------------------------------------
__global__ __launch_bounds__(256, 2) void attn_fused(
    const unsigned short* __restrict__ xh, const int* __restrict__ sl32,
    float* __restrict__ attn, unsigned int* __restrict__ cpart)
{
  __shared__ __align__(16) unsigned short kbuf[64 * 64];   // 8 KB: 64-key chunk
  __shared__ __align__(16) unsigned int ebuf[8][2048];     // 64 KB e' row-pairs
  __shared__ float wbuf[4][16];
  __shared__ float invbuf[16];

  const int n    = blockIdx.x;
  const int xcd  = n & 7;
  const int slot = n >> 3;                 // 0..1023 per XCD
  const int bh   = (slot >> 7) * 8 + xcd;  // 8 bh-slices per XCD
  const int qt   = slot & 127;             // 128 q-tiles of 16 rows
  const int b    = bh >> 4;
  const int tid  = threadIdx.x;
  const int wv   = tid >> 6;
  const int lane = tid & 63;
  const int lo   = lane & 15;
  const int g    = lane >> 4;

  // seq_lens dtype auto-detect (values >= 1024 -> int64 layout has word1==0)
  const bool is64 = (sl32[1] == 0);
  const int seqlen = is64 ? sl32[2 * b] : sl32[b];

  const unsigned short* xk = xh + (size_t)bh * S_ * 64;

  // Q fragment (A-frag): row = lo, k = g*8 + i (+32)
  short8 aq0 = *(const short8*)(xk + (size_t)(qt * 16 + lo) * 64 + g * 8);
  short8 aq1 = *(const short8*)(xk + (size_t)(qt * 16 + lo) * 64 + g * 8 + 32);

  // Staging: thread -> key row sr (0..63), unit-pair up (0..3), 32B each.
  const int sr = tid >> 2, up = tid & 3;
  uint4 pf0, pf1;
  auto prefetch = [&](int c) {
    const uint4* src = (const uint4*)(xk + (size_t)(c * 64 + sr) * 64) + up * 2;
    pf0 = src[0]; pf1 = src[1];
  };
  auto commit = [&]() {
    uint4* d = (uint4*)&kbuf[sr * 64];
    const int sw = sr & 7;
    d[(up * 2) ^ sw]     = pf0;
    d[(up * 2 + 1) ^ sw] = pf1;
  };

  // ---------------- Compute pass: QK^T + exp -> ebuf ----------------
  float rsum[4] = {0.f, 0.f, 0.f, 0.f};
  prefetch(0);
  commit();
  __syncthreads();
  const int lk = wv * 16 + lo;             // my tile's local key row
  const int cs = g ^ (lk & 7);
  const int sA = ((g * 2) & 6) << 2;       // ebuf col swizzle {0,8,16,24}
  for (int c = 0; c < 32; ++c) {
    if (c < 31) prefetch(c + 1);
    short8 b0 = *(const short8*)&kbuf[lk * 64 + cs * 8];
    short8 b1 = *(const short8*)&kbuf[lk * 64 + (cs ^ 4) * 8];
    f32x4 acc = {0.f, 0.f, 0.f, 0.f};
    acc = __builtin_amdgcn_mfma_f32_16x16x32_bf16(aq0, b0, acc, 0, 0, 0);
    acc = __builtin_amdgcn_mfma_f32_16x16x32_bf16(aq1, b1, acc, 0, 0, 0);
    const int kg = c * 64 + lk;            // global key/col index
    const bool valid = kg < seqlen;
    float e0 = valid ? exp2f(acc[0] * SCL - EBIAS) : 0.f;
    float e1 = valid ? exp2f(acc[1] * SCL - EBIAS) : 0.f;
    float e2 = valid ? exp2f(acc[2] * SCL - EBIAS) : 0.f;
    float e3 = valid ? exp2f(acc[3] * SCL - EBIAS) : 0.f;
    rsum[0] += e0; rsum[1] += e1; rsum[2] += e2; rsum[3] += e3;
    // rows g*4+{0,1} -> pair r2=g*2 ; rows g*4+{2,3} -> pair r2=g*2+1
    ebuf[g * 2][kg ^ sA] =
        __builtin_bit_cast(unsigned int, __builtin_amdgcn_cvt_pkrtz(e0, e1));
    ebuf[g * 2 + 1][kg ^ sA] =
        __builtin_bit_cast(unsigned int, __builtin_amdgcn_cvt_pkrtz(e2, e3));
    __syncthreads();                       // kbuf consumed by all waves
    if (c < 31) commit();
    __syncthreads();                       // kbuf refreshed
  }

  // ---------------- Row sums -> 1/l ----------------
#pragma unroll
  for (int r = 0; r < 4; ++r) {
    float v = rsum[r];
    v += __shfl_xor(v, 1);
    v += __shfl_xor(v, 2);
    v += __shfl_xor(v, 4);
    v += __shfl_xor(v, 8);
    if (lo == 0) wbuf[wv][g * 4 + r] = v;
  }
  __syncthreads();
  if (tid < 16)
    invbuf[tid] = 1.0f / (wbuf[0][tid] + wbuf[1][tid] + wbuf[2][tid] + wbuf[3][tid]);
  __syncthreads();

  // ---------------- Write phase: 256B-contiguous nt stores ----------------
  const int wr = tid >> 4, wc = tid & 15;  // row 0..15, col group 0..15
  const int r2w = wr >> 1, shw = (wr & 1) * 16, sw2 = (r2w & 6) << 2;
  const float vr = invbuf[wr];
  float* prow = attn + (size_t)bh * S_ * S_ + (size_t)(qt * 16 + wr) * S_;
#pragma unroll 8
  for (int i = 0; i < 32; ++i) {
    const int k0 = wc * 4 + i * 64;
    uint4 u = *(const uint4*)&ebuf[r2w][k0 ^ sw2];
    f32x4 v = {h2f(u.x, shw) * vr, h2f(u.y, shw) * vr,
               h2f(u.z, shw) * vr, h2f(u.w, shw) * vr};
    __builtin_nontemporal_store(v, (f32x4*)(prow + k0));
  }

  // ---------------- Column sums -> fp16 cpart (deterministic) -------------
  const int c0 = tid * 8;
  float a0 = 0.f, a1 = 0.f, a2 = 0.f, a3 = 0.f;
  float a4 = 0.f, a5 = 0.f, a6 = 0.f, a7 = 0.f;
#pragma unroll
  for (int r2 = 0; r2 < 8; ++r2) {
    const int s = (r2 & 6) << 2;
    const uint4 uA = *(const uint4*)&ebuf[r2][c0 ^ s];
    const uint4 uB = *(const uint4*)&ebuf[r2][(c0 ^ s) + 4];
    const float i0 = invbuf[2 * r2], i1 = invbuf[2 * r2 + 1];
    a0 += h2f(uA.x, 0) * i0 + h2f(uA.x, 16) * i1;
    a1 += h2f(uA.y, 0) * i0 + h2f(uA.y, 16) * i1;
    a2 += h2f(uA.z, 0) * i0 + h2f(uA.z, 16) * i1;
    a3 += h2f(uA.w, 0) * i0 + h2f(uA.w, 16) * i1;
    a4 += h2f(uB.x, 0) * i0 + h2f(uB.x, 16) * i1;
    a5 += h2f(uB.y, 0) * i0 + h2f(uB.y, 16) * i1;
    a6 += h2f(uB.z, 0) * i0 + h2f(uB.z, 16) * i1;
    a7 += h2f(uB.w, 0) * i0 + h2f(uB.w, 16) * i1;
  }
  uint4 w;
  w.x = __builtin_bit_cast(unsigned int, __builtin_amdgcn_cvt_pkrtz(a0, a1));
  w.y = __builtin_bit_cast(unsigned int, __builtin_amdgcn_cvt_pkrtz(a2, a3));
  w.z = __builtin_bit_cast(unsigned int, __builtin_amdgcn_cvt_pkrtz(a4, a5));
  w.w = __builtin_bit_cast(unsigned int, __builtin_amdgcn_cvt_pkrtz(a6, a7));
  *(uint4*)&cpart[(size_t)(bh * 128 + qt) * 1024 + tid * 4] = w;
}

// c[bh][k] = sum over 128 q-tiles of fp16 cpart
__global__ __launch_bounds__(256) void creduce(const unsigned int* __restrict__ cpart,
                                               float* __restrict__ c) {
  const int i = blockIdx.x * 256 + threadIdx.x;   // 64*2048 total
  const int bh = i >> 11, k = i & 2047;
  const unsigned short* cp = (const unsigned short*)cpart + (size_t)bh * 128 * 2048 + k;
  float s = 0.f;
#pragma unroll 8
  for (int qt = 0; qt < 128; ++qt)
    s += (float)__builtin_bit_cast(_Float16, cp[(size_t)qt * 2048]);
  c[i] = s;
}

// csump[oct][bh][d] = sum over oct's 256 keys of c[bh][k] * xh[bh][k][d]
__global__ __launch_bounds__(256) void csum_k(const float* __restrict__ c,
                                              const unsigned short* __restrict__ xh,
                                              float* __restrict__ csump) {
  __shared__ float part[4][64];
  const int bh = blockIdx.x >> 3, oct = blockIdx.x & 7;
  const int seg = threadIdx.x >> 6, d = threadIdx.x & 63;
  const float* cb = c + bh * 2048;
  const unsigned short* xb = xh + (size_t)bh * S_ * 64 + d;
  const int k0 = oct * 256 + seg * 64;
  float acc = 0.f;
#pragma unroll 4
  for (int k = k0; k < k0 + 64; ++k) {
    float xv = __uint_as_float((unsigned int)xb[(size_t)k * 64] << 16);
    acc += cb[k] * xv;
  }
  part[seg][d] = acc;
  __syncthreads();
  if (threadIdx.x < 64)
    csump[((size_t)oct * 64 + bh) * 64 + d] =
        part[0][d] + part[1][d] + part[2][d] + part[3][d];
}

// out0[b][d] = sum_e csum[b][e] * W[d][e] + S * bias[d], csum = sum of octants
__global__ __launch_bounds__(256) void proj_k(const float* __restrict__ csump,
                                              const float* __restrict__ W,
                                              const float* __restrict__ bias,
                                              float* __restrict__ out0) {
  const int idx = blockIdx.x * 4 + (threadIdx.x >> 6); // (b,d) pair per wave
  const int b = idx >> 10, d = idx & 1023;
  const int lane = threadIdx.x & 63;
  const float* wr = W + (size_t)d * D_;
  float acc = 0.f;
#pragma unroll
  for (int e = 0; e < 16; ++e) {
    const int ei = lane + e * 64;            // e index within D
    const int bhh = b * 16 + (ei >> 6);      // bh of this e
    const int dd = ei & 63;
    float cv = 0.f;
#pragma unroll
    for (int oct = 0; oct < 8; ++oct)
      cv += csump[((size_t)oct * 64 + bhh) * 64 + dd];
    acc += cv * wr[ei];
  }
  acc += __shfl_xor(acc, 32);
  acc += __shfl_xor(acc, 16);
  acc += __shfl_xor(acc, 8);
  acc += __shfl_xor(acc, 4);
  acc += __shfl_xor(acc, 2);
  acc += __shfl_xor(acc, 1);
  if (lane == 0) out0[idx] = acc + 2048.0f * bias[d];
}

extern "C" void kernel_launch(void* const* d_in, const int* in_sizes, int n_in,
                              void* d_out, int out_size, void* d_ws, size_t ws_size,
                              hipStream_t stream) {
  const float* x    = (const float*)d_in[0];
  const int*   sl   = (const int*)d_in[1];
  const float* W    = (const float*)d_in[2];
  const float* bias = (const float*)d_in[3];

  float* out0 = (float*)d_out;
  float* attn = out0 + B_ * D_;

  unsigned int* cpart = (unsigned int*)d_ws;              // 64*128*1024 u32 = 33.5 MB
  float* c     = (float*)(cpart + (size_t)64 * 128 * 1024); // 512 KB
  float* csump = c + 64 * 2048;                            // 128 KB
  unsigned short* xh = (unsigned short*)(csump + 8 * 64 * 64); // bf16, 16 MB

  hipLaunchKernelGGL(xcvt,       dim3(2048), dim3(256), 0, stream, x, xh);
  hipLaunchKernelGGL(attn_fused, dim3(8192), dim3(256), 0, stream, xh, sl, attn, cpart);
  hipLaunchKernelGGL(creduce,    dim3(512),  dim3(256), 0, stream, cpart, c);
  hipLaunchKernelGGL(csum_k,     dim3(512),  dim3(256), 0, stream, c, xh, csump);
  hipLaunchKernelGGL(proj_k,     dim3(1024), dim3(256), 0, stream, csump, W, bias, out0);
}

// Round 10
// 309.434 us; speedup vs baseline: 2.1479x; 1.0414x over previous
//
#include <hip/hip_runtime.h>

// Problem constants
#define S_  2048
#define D_  1024
#define H_  16
#define B_  4

typedef __attribute__((ext_vector_type(8))) short short8;
typedef __attribute__((ext_vector_type(4))) float f32x4;

__device__ __forceinline__ unsigned short f2bf(float f) {
  unsigned int u = __float_as_uint(f);
  u += 0x7fffu + ((u >> 16) & 1u);      // round-to-nearest-even
  return (unsigned short)(u >> 16);
}
__device__ __forceinline__ unsigned int pack2(float a, float b) {
  return (unsigned int)f2bf(a) | ((unsigned int)f2bf(b) << 16);
}
__device__ __forceinline__ float h2f(unsigned int u, int shft) {
  unsigned short hs = (unsigned short)(u >> shft);
  return (float)__builtin_bit_cast(_Float16, hs);
}

// 0.125 (1/sqrt(DK)) * log2(e): use exp2 (native v_exp_f32)
#define SCL   0.18033688011112042f
#define EBIAS 12.0f   // keeps e' in fp16 range; cancels in softmax (R2/R8/R9-validated)

// ---------------------------------------------------------------------------
// x (B,S,D) f32 -> xh (B,H,S,64) bf16 head-major (256 KB contiguous per bh).
// ---------------------------------------------------------------------------
__global__ __launch_bounds__(256) void xcvt(const float* __restrict__ x,
                                            unsigned short* __restrict__ xh) {
  const int n = blockIdx.x;
  const int bh = n >> 5, chunk = n & 31;
  const int b = bh >> 4, h = bh & 15;
  const int r = threadIdx.x >> 2, cg = threadIdx.x & 3;
  const int srow = chunk * 64 + r;
  const float* src = x + ((size_t)b * S_ + srow) * D_ + h * 64 + cg * 16;
  float4 v0 = ((const float4*)src)[0];
  float4 v1 = ((const float4*)src)[1];
  float4 v2 = ((const float4*)src)[2];
  float4 v3 = ((const float4*)src)[3];
  uint4 w0, w1;
  w0.x = pack2(v0.x, v0.y); w0.y = pack2(v0.z, v0.w);
  w0.z = pack2(v1.x, v1.y); w0.w = pack2(v1.z, v1.w);
  w1.x = pack2(v2.x, v2.y); w1.y = pack2(v2.z, v2.w);
  w1.z = pack2(v3.x, v3.y); w1.w = pack2(v3.z, v3.w);
  unsigned short* dst = xh + ((size_t)bh * S_ + srow) * 64 + cg * 16;
  *(uint4*)dst = w0;
  *(uint4*)(dst + 8) = w1;
}

// ---------------------------------------------------------------------------
// Single-pass fused attention (R9 structure + double-buffered kbuf).
// Block = 256 thr (4 waves), one 16-row q-tile, full S keys.
// Per 64-key chunk (wave w owns tile w): prefetch(c+1) at top, compute(c)
// from kbuf[c&1], commit(c+1) into the other buffer, ONE barrier. Loads get
// a full chunk of MFMA+exp to cover L2 latency; 32 barriers total (was 64).
// e' packed fp16 row-pairs -> ebuf[8][2048] u32, col XOR-swizzle (2-way max).
// Write phase: 256B-contiguous nt stores. Column sums in-thread -> fp16
// cpart (deterministic, no atomics).
// LDS = 16K kbuf + 64K ebuf = 81920 B exactly -> 2 blocks/CU; wbuf/invbuf
// alias dead kbuf space after the compute loop.
// grid = 64 bh * 128 qt = 8192, XCD-swizzled (8 bh per XCD, L2-resident K).
// ---------------------------------------------------------------------------
__global__ __launch_bounds__(256, 2) void attn_fused(
    const unsigned short* __restrict__ xh, const int* __restrict__ sl32,
    float* __restrict__ attn, unsigned int* __restrict__ cpart)
{
  __shared__ __align__(16) unsigned short kbuf[2][64 * 64]; // 16 KB dbuf
  __shared__ __align__(16) unsigned int ebuf[8][2048];      // 64 KB e' pairs
  float* wbuf   = (float*)&kbuf[0][0];    // [4][16], valid after compute loop
  float* invbuf = (float*)&kbuf[1][0];    // [16]

  const int n    = blockIdx.x;
  const int xcd  = n & 7;
  const int slot = n >> 3;                 // 0..1023 per XCD
  const int bh   = (slot >> 7) * 8 + xcd;  // 8 bh-slices per XCD
  const int qt   = slot & 127;             // 128 q-tiles of 16 rows
  const int b    = bh >> 4;
  const int tid  = threadIdx.x;
  const int wv   = tid >> 6;
  const int lane = tid & 63;
  const int lo   = lane & 15;
  const int g    = lane >> 4;

  // seq_lens dtype auto-detect (values >= 1024 -> int64 layout has word1==0)
  const bool is64 = (sl32[1] == 0);
  const int seqlen = is64 ? sl32[2 * b] : sl32[b];

  const unsigned short* xk = xh + (size_t)bh * S_ * 64;

  // Q fragment (A-frag): row = lo, k = g*8 + i (+32)
  short8 aq0 = *(const short8*)(xk + (size_t)(qt * 16 + lo) * 64 + g * 8);
  short8 aq1 = *(const short8*)(xk + (size_t)(qt * 16 + lo) * 64 + g * 8 + 32);

  // Staging: thread -> key row sr (0..63), unit-pair up (0..3), 32B each.
  const int sr = tid >> 2, up = tid & 3;
  uint4 pf0, pf1;
  auto prefetch = [&](int c) {
    const uint4* src = (const uint4*)(xk + (size_t)(c * 64 + sr) * 64) + up * 2;
    pf0 = src[0]; pf1 = src[1];
  };
  auto commit = [&](unsigned short* dst) {
    uint4* d = (uint4*)&dst[sr * 64];
    const int sw = sr & 7;
    d[(up * 2) ^ sw]     = pf0;
    d[(up * 2 + 1) ^ sw] = pf1;
  };

  // ---------------- Compute pass: QK^T + exp -> ebuf ----------------
  float rsum[4] = {0.f, 0.f, 0.f, 0.f};
  prefetch(0);
  commit(kbuf[0]);
  __syncthreads();
  const int lk = wv * 16 + lo;             // my tile's local key row
  const int cs = g ^ (lk & 7);
  const int sA = ((g * 2) & 6) << 2;       // ebuf col swizzle {0,8,16,24}
  for (int c = 0; c < 32; ++c) {
    if (c < 31) prefetch(c + 1);
    const unsigned short* kb = kbuf[c & 1];
    short8 b0 = *(const short8*)&kb[lk * 64 + cs * 8];
    short8 b1 = *(const short8*)&kb[lk * 64 + (cs ^ 4) * 8];
    f32x4 acc = {0.f, 0.f, 0.f, 0.f};
    acc = __builtin_amdgcn_mfma_f32_16x16x32_bf16(aq0, b0, acc, 0, 0, 0);
    acc = __builtin_amdgcn_mfma_f32_16x16x32_bf16(aq1, b1, acc, 0, 0, 0);
    const int kg = c * 64 + lk;            // global key/col index
    const bool valid = kg < seqlen;
    float e0 = valid ? exp2f(acc[0] * SCL - EBIAS) : 0.f;
    float e1 = valid ? exp2f(acc[1] * SCL - EBIAS) : 0.f;
    float e2 = valid ? exp2f(acc[2] * SCL - EBIAS) : 0.f;
    float e3 = valid ? exp2f(acc[3] * SCL - EBIAS) : 0.f;
    rsum[0] += e0; rsum[1] += e1; rsum[2] += e2; rsum[3] += e3;
    ebuf[g * 2][kg ^ sA] =
        __builtin_bit_cast(unsigned int, __builtin_amdgcn_cvt_pkrtz(e0, e1));
    ebuf[g * 2 + 1][kg ^ sA] =
        __builtin_bit_cast(unsigned int, __builtin_amdgcn_cvt_pkrtz(e2, e3));
    // commit(c+1) into the buffer last read at chunk c-1 (barrier-separated)
    if (c < 31) commit(kbuf[(c + 1) & 1]);
    __syncthreads();
  }

  // ---------------- Row sums -> 1/l (wbuf aliases dead kbuf) --------------
#pragma unroll
  for (int r = 0; r < 4; ++r) {
    float v = rsum[r];
    v += __shfl_xor(v, 1);
    v += __shfl_xor(v, 2);
    v += __shfl_xor(v, 4);
    v += __shfl_xor(v, 8);
    if (lo == 0) wbuf[wv * 16 + g * 4 + r] = v;
  }
  __syncthreads();
  if (tid < 16)
    invbuf[tid] = 1.0f / (wbuf[tid] + wbuf[16 + tid] + wbuf[32 + tid] + wbuf[48 + tid]);
  __syncthreads();

  // ---------------- Write phase: 256B-contiguous nt stores ----------------
  const int wr = tid >> 4, wc = tid & 15;  // row 0..15, col group 0..15
  const int r2w = wr >> 1, shw = (wr & 1) * 16, sw2 = (r2w & 6) << 2;
  const float vr = invbuf[wr];
  float* prow = attn + (size_t)bh * S_ * S_ + (size_t)(qt * 16 + wr) * S_;
#pragma unroll 8
  for (int i = 0; i < 32; ++i) {
    const int k0 = wc * 4 + i * 64;
    uint4 u = *(const uint4*)&ebuf[r2w][k0 ^ sw2];
    f32x4 v = {h2f(u.x, shw) * vr, h2f(u.y, shw) * vr,
               h2f(u.z, shw) * vr, h2f(u.w, shw) * vr};
    __builtin_nontemporal_store(v, (f32x4*)(prow + k0));
  }

  // ---------------- Column sums -> fp16 cpart (deterministic) -------------
  const int c0 = tid * 8;
  float a0 = 0.f, a1 = 0.f, a2 = 0.f, a3 = 0.f;
  float a4 = 0.f, a5 = 0.f, a6 = 0.f, a7 = 0.f;
#pragma unroll
  for (int r2 = 0; r2 < 8; ++r2) {
    const int s = (r2 & 6) << 2;
    const uint4 uA = *(const uint4*)&ebuf[r2][c0 ^ s];
    const uint4 uB = *(const uint4*)&ebuf[r2][(c0 ^ s) + 4];
    const float i0 = invbuf[2 * r2], i1 = invbuf[2 * r2 + 1];
    a0 += h2f(uA.x, 0) * i0 + h2f(uA.x, 16) * i1;
    a1 += h2f(uA.y, 0) * i0 + h2f(uA.y, 16) * i1;
    a2 += h2f(uA.z, 0) * i0 + h2f(uA.z, 16) * i1;
    a3 += h2f(uA.w, 0) * i0 + h2f(uA.w, 16) * i1;
    a4 += h2f(uB.x, 0) * i0 + h2f(uB.x, 16) * i1;
    a5 += h2f(uB.y, 0) * i0 + h2f(uB.y, 16) * i1;
    a6 += h2f(uB.z, 0) * i0 + h2f(uB.z, 16) * i1;
    a7 += h2f(uB.w, 0) * i0 + h2f(uB.w, 16) * i1;
  }
  uint4 w;
  w.x = __builtin_bit_cast(unsigned int, __builtin_amdgcn_cvt_pkrtz(a0, a1));
  w.y = __builtin_bit_cast(unsigned int, __builtin_amdgcn_cvt_pkrtz(a2, a3));
  w.z = __builtin_bit_cast(unsigned int, __builtin_amdgcn_cvt_pkrtz(a4, a5));
  w.w = __builtin_bit_cast(unsigned int, __builtin_amdgcn_cvt_pkrtz(a6, a7));
  *(uint4*)&cpart[(size_t)(bh * 128 + qt) * 1024 + tid * 4] = w;
}

// Fused creduce + csum_k:
// phase 1: c[k] = sum over 128 q-tiles of fp16 cpart  (k in this oct)
// phase 2: csump[oct][bh][d] = sum over oct's 256 keys of c[k] * xh[bh][k][d]
__global__ __launch_bounds__(256) void csum2(const unsigned int* __restrict__ cpart,
                                             const unsigned short* __restrict__ xh,
                                             float* __restrict__ csump) {
  __shared__ float csh[256];
  __shared__ float part[4][64];
  const int bh = blockIdx.x >> 3, oct = blockIdx.x & 7;
  const int t = threadIdx.x;
  {
    const int k = oct * 256 + t;
    const unsigned short* cp =
        (const unsigned short*)cpart + (size_t)bh * 128 * 2048 + k;
    float s = 0.f;
#pragma unroll 8
    for (int q = 0; q < 128; ++q)
      s += (float)__builtin_bit_cast(_Float16, cp[(size_t)q * 2048]);
    csh[t] = s;
  }
  __syncthreads();
  const int seg = t >> 6, d = t & 63;
  const unsigned short* xb = xh + (size_t)bh * S_ * 64 + d;
  const int k0 = oct * 256 + seg * 64;
  float acc = 0.f;
#pragma unroll 4
  for (int kk = 0; kk < 64; ++kk) {
    float xv = __uint_as_float((unsigned int)xb[(size_t)(k0 + kk) * 64] << 16);
    acc += csh[seg * 64 + kk] * xv;
  }
  part[seg][d] = acc;
  __syncthreads();
  if (t < 64)
    csump[((size_t)oct * 64 + bh) * 64 + d] =
        part[0][d] + part[1][d] + part[2][d] + part[3][d];
}

// out0[b][d] = sum_e csum[b][e] * W[d][e] + S * bias[d], csum = sum of octants
__global__ __launch_bounds__(256) void proj_k(const float* __restrict__ csump,
                                              const float* __restrict__ W,
                                              const float* __restrict__ bias,
                                              float* __restrict__ out0) {
  const int idx = blockIdx.x * 4 + (threadIdx.x >> 6); // (b,d) pair per wave
  const int b = idx >> 10, d = idx & 1023;
  const int lane = threadIdx.x & 63;
  const float* wr = W + (size_t)d * D_;
  float acc = 0.f;
#pragma unroll
  for (int e = 0; e < 16; ++e) {
    const int ei = lane + e * 64;            // e index within D
    const int bhh = b * 16 + (ei >> 6);      // bh of this e
    const int dd = ei & 63;
    float cv = 0.f;
#pragma unroll
    for (int oct = 0; oct < 8; ++oct)
      cv += csump[((size_t)oct * 64 + bhh) * 64 + dd];
    acc += cv * wr[ei];
  }
  acc += __shfl_xor(acc, 32);
  acc += __shfl_xor(acc, 16);
  acc += __shfl_xor(acc, 8);
  acc += __shfl_xor(acc, 4);
  acc += __shfl_xor(acc, 2);
  acc += __shfl_xor(acc, 1);
  if (lane == 0) out0[idx] = acc + 2048.0f * bias[d];
}

extern "C" void kernel_launch(void* const* d_in, const int* in_sizes, int n_in,
                              void* d_out, int out_size, void* d_ws, size_t ws_size,
                              hipStream_t stream) {
  const float* x    = (const float*)d_in[0];
  const int*   sl   = (const int*)d_in[1];
  const float* W    = (const float*)d_in[2];
  const float* bias = (const float*)d_in[3];

  float* out0 = (float*)d_out;
  float* attn = out0 + B_ * D_;

  unsigned int* cpart = (unsigned int*)d_ws;                // 64*128*1024 u32 = 33.5 MB
  float* csump = (float*)(cpart + (size_t)64 * 128 * 1024); // 8*64*64 f32 = 128 KB
  unsigned short* xh = (unsigned short*)(csump + 8 * 64 * 64); // bf16, 16 MB

  hipLaunchKernelGGL(xcvt,       dim3(2048), dim3(256), 0, stream, x, xh);
  hipLaunchKernelGGL(attn_fused, dim3(8192), dim3(256), 0, stream, xh, sl, attn, cpart);
  hipLaunchKernelGGL(csum2,      dim3(512),  dim3(256), 0, stream, cpart, xh, csump);
  hipLaunchKernelGGL(proj_k,     dim3(1024), dim3(256), 0, stream, csump, W, bias, out0);
}